// Round 2
// baseline (363.883 us; speedup 1.0000x reference)
//
#include <hip/hip_runtime.h>
#include <hip/hip_bf16.h>

#define HW 1024
#define C_CH 768
#define BATCH 16
#define NG 32
#define CPG 24
#define EPS 1e-5f

typedef __attribute__((ext_vector_type(8))) short bf16x8;
typedef __attribute__((ext_vector_type(4))) float f32x4;
typedef unsigned short u16;
typedef unsigned int u32;

typedef const __attribute__((address_space(1))) void* gas_ptr;
typedef __attribute__((address_space(3))) void* las_ptr;

__device__ __forceinline__ void load_lds16(const void* g, void* l) {
    __builtin_amdgcn_global_load_lds((gas_ptr)g, (las_ptr)l, 16, 0, 0);
}

__device__ __forceinline__ u16 f2bf(float f) {
    __hip_bfloat16 h = __float2bfloat16(f);
    return *(u16*)&h;
}
__device__ __forceinline__ float bf2f(u16 u) {
    return __uint_as_float(((u32)u) << 16);
}

// ---------------- cast f32 -> bf16 (vectorized x4) ----------------
__global__ __launch_bounds__(256) void cast_bf16_kernel(const float4* __restrict__ in,
                                                        ushort4* __restrict__ out, int n4) {
    int i = blockIdx.x * 256 + threadIdx.x;
    if (i >= n4) return;
    float4 v = in[i];
    ushort4 u;
    u.x = f2bf(v.x); u.y = f2bf(v.y); u.z = f2bf(v.z); u.w = f2bf(v.w);
    out[i] = u;
}

// ---------------- GroupNorm stats: one block per (b,g) ----------------
__global__ __launch_bounds__(256) void gn_stats_kernel(const float* __restrict__ x,
                                                       float* __restrict__ stats) {
    int bg = blockIdx.x;                       // b*NG + g
    const float4* p4 = (const float4*)(x + (size_t)bg * (CPG * HW));
    float s = 0.f, s2 = 0.f;
    for (int i = threadIdx.x; i < (CPG * HW) / 4; i += 256) {
        float4 v = p4[i];
        s  += v.x + v.y + v.z + v.w;
        s2 += v.x * v.x + v.y * v.y + v.z * v.z + v.w * v.w;
    }
    int lane = threadIdx.x & 63, wid = threadIdx.x >> 6;
    for (int off = 32; off; off >>= 1) {
        s  += __shfl_xor(s,  off, 64);
        s2 += __shfl_xor(s2, off, 64);
    }
    __shared__ float red[8];
    if (lane == 0) { red[wid * 2] = s; red[wid * 2 + 1] = s2; }
    __syncthreads();
    if (threadIdx.x == 0) {
        s = red[0] + red[2] + red[4] + red[6];
        s2 = red[1] + red[3] + red[5] + red[7];
        float mean = s / (float)(CPG * HW);
        float var  = s2 / (float)(CPG * HW) - mean * mean;
        stats[2 * bg]     = mean;
        stats[2 * bg + 1] = rsqrtf(var + EPS);
    }
}

// ------------- GroupNorm normalize + transpose -> xn_T [B, HW, C] bf16 -------------
__global__ __launch_bounds__(256) void gn_norm_kernel(const float* __restrict__ x,
                                                      const float* __restrict__ stats,
                                                      const float* __restrict__ gamma,
                                                      const float* __restrict__ beta,
                                                      __hip_bfloat16* __restrict__ xnT) {
    __shared__ float lds[64][65];
    int b  = blockIdx.y;
    int p0 = blockIdx.x * 64;
    int t = threadIdx.x;
    int lane = t & 63;
    int grp  = t >> 6;   // 0..3
    for (int cc = 0; cc < C_CH / 64; cc++) {
        int c0 = cc * 64;
        for (int i = 0; i < 16; i++) {
            int c = c0 + grp * 16 + i;
            float2 st = ((const float2*)stats)[b * NG + c / CPG];
            float ga = gamma[c], be = beta[c];
            float v = x[((size_t)b * C_CH + c) * HW + p0 + lane];
            lds[lane][grp * 16 + i] = (v - st.x) * st.y * ga + be;
        }
        __syncthreads();
        for (int i = 0; i < 16; i++) {
            int pp = grp * 16 + i;
            xnT[((size_t)b * HW + p0 + pp) * C_CH + c0 + lane] =
                __float2bfloat16(lds[pp][lane]);
        }
        __syncthreads();
    }
}

// ---------------- row softmax over att [rows][768] bf16, in place ----------------
__global__ __launch_bounds__(256) void softmax_kernel(__hip_bfloat16* __restrict__ att) {
    int row  = blockIdx.x * 4 + (threadIdx.x >> 6);
    int lane = threadIdx.x & 63;
    u16* p = (u16*)(att + (size_t)row * C_CH);
    float v[12];
    float m = -1e30f;
    for (int j = 0; j < 12; j++) {
        v[j] = bf2f(p[j * 64 + lane]);
        m = fmaxf(m, v[j]);
    }
    for (int off = 32; off; off >>= 1) m = fmaxf(m, __shfl_xor(m, off, 64));
    float s = 0.f;
    for (int j = 0; j < 12; j++) { v[j] = __expf(v[j] - m); s += v[j]; }
    for (int off = 32; off; off >>= 1) s += __shfl_xor(s, off, 64);
    float inv = 1.0f / s;
    for (int j = 0; j < 12; j++) p[j * 64 + lane] = f2bf(v[j] * inv);
}

// ---------------- NT GEMM: C[m,n] = scale * sum_k A[m,k]*B[n,k] (+bias/res) ----------------
// A: [M x K] row-major, B: [N x K] row-major. Tile 128x128, BK=64, 4 waves of 64x64.
// 2-phase pipeline: double-buffered LDS, next-tile global_load_lds issued BEFORE
// the current tile's ds_read+MFMA, single __syncthreads (vmcnt(0) drain) per K-step.
// Staging uses XOR-swizzled global source so ds_read_b128 frag reads are conflict-free.
template<int OUT_F32>
__global__ __launch_bounds__(256, 2) void gemm_nt_kernel(
    const __hip_bfloat16* __restrict__ A, long sA,
    const __hip_bfloat16* __restrict__ B, long sB,
    void* __restrict__ Cout, long sC, int ldc,
    int K, float scale,
    const float* __restrict__ bias_row,
    const float* __restrict__ bias_col,
    const float* __restrict__ residual, long sR)
{
    __shared__ __hip_bfloat16 ldsA[2][128 * 64];
    __shared__ __hip_bfloat16 ldsB[2][128 * 64];
    const int t  = threadIdx.x;
    const int b  = blockIdx.z;
    const int m0 = blockIdx.y * 128;
    const int n0 = blockIdx.x * 128;
    const int lane = t & 63;
    const int wid  = t >> 6;
    const int wm = wid >> 1, wn = wid & 1;
    const int lrow = lane & 15, lk = lane >> 4;

    // staging: chunk idx = r*256 + t -> row = idx/8, chunk = idx%8 (16B chunks)
    const int srow   = t >> 3;                       // + r*32
    const int schunk = t & 7;
    const int kphys  = (schunk ^ (srow & 7)) * 8;    // element offset in [0,64)

    const __hip_bfloat16* aBase = A + (size_t)b * sA + (size_t)(m0 + srow) * K + kphys;
    const __hip_bfloat16* bBase = B + (size_t)b * sB + (size_t)(n0 + srow) * K + kphys;
    const int ldsDst = (t & ~63) * 8;                // wave-uniform elem offset; +r*2048

    f32x4 acc[4][4] = {};

    const int nk = K >> 6;

    auto stage = [&](int buf, int kt) {
        const __hip_bfloat16* ak = aBase + (size_t)kt * 64;
        const __hip_bfloat16* bk = bBase + (size_t)kt * 64;
        for (int r = 0; r < 4; r++)
            load_lds16(ak + (size_t)r * 32 * K, &ldsA[buf][ldsDst + r * 2048]);
        for (int r = 0; r < 4; r++)
            load_lds16(bk + (size_t)r * 32 * K, &ldsB[buf][ldsDst + r * 2048]);
    };

    stage(0, 0);
    __syncthreads();   // buf0 ready (implicit vmcnt(0) before barrier)

    int cur = 0;
    for (int kt = 0; kt < nk; kt++) {
        if (kt + 1 < nk) stage(cur ^ 1, kt + 1);   // prefetch next tile (in flight during MFMA)
        for (int h = 0; h < 2; h++) {
            bf16x8 af[4], bfr[4];
            const int lc = h * 4 + lk;
            for (int i = 0; i < 4; i++) {
                int row = wm * 64 + i * 16 + lrow;
                int pc = lc ^ (row & 7);
                af[i] = *(const bf16x8*)&ldsA[cur][row * 64 + pc * 8];
            }
            for (int i = 0; i < 4; i++) {
                int col = wn * 64 + i * 16 + lrow;
                int pc = lc ^ (col & 7);
                bfr[i] = *(const bf16x8*)&ldsB[cur][col * 64 + pc * 8];
            }
            for (int i = 0; i < 4; i++)
                for (int j = 0; j < 4; j++)
                    acc[i][j] = __builtin_amdgcn_mfma_f32_16x16x32_bf16(
                        af[i], bfr[j], acc[i][j], 0, 0, 0);
        }
        if (kt + 1 < nk) {
            __syncthreads();   // drains prefetch vmcnt(0); all waves done reading cur
            cur ^= 1;
        }
    }

    __hip_bfloat16* outB = (__hip_bfloat16*)Cout;
    float* outF = (float*)Cout;
    for (int i = 0; i < 4; i++)
        for (int j = 0; j < 4; j++) {
            int row = m0 + wm * 64 + i * 16 + lk * 4;
            int col = n0 + wn * 64 + j * 16 + lrow;
            f32x4 a = acc[i][j];
            for (int r = 0; r < 4; r++) {
                int rr = row + r;
                float v = a[r] * scale;
                if (bias_row) v += bias_row[rr];
                if (bias_col) v += bias_col[col];
                if (residual) v += residual[(size_t)b * sR + (size_t)rr * ldc + col];
                size_t off = (size_t)b * sC + (size_t)rr * ldc + col;
                if (OUT_F32) outF[off] = v;
                else         outB[off] = __float2bfloat16(v);
            }
        }
}

extern "C" void kernel_launch(void* const* d_in, const int* in_sizes, int n_in,
                              void* d_out, int out_size, void* d_ws, size_t ws_size,
                              hipStream_t stream) {
    const float* x     = (const float*)d_in[0];
    const float* gamma = (const float*)d_in[1];
    const float* beta  = (const float*)d_in[2];
    const float* w_qkv = (const float*)d_in[3];
    const float* b_qkv = (const float*)d_in[4];
    const float* w_out = (const float*)d_in[5];
    const float* b_out = (const float*)d_in[6];

    char* ws = (char*)d_ws;
    size_t off = 0;
    auto alloc = [&](size_t bytes) {
        void* p = ws + off;
        off += (bytes + 255) & ~(size_t)255;
        return p;
    };
    __hip_bfloat16* xnT   = (__hip_bfloat16*)alloc((size_t)BATCH * HW * C_CH * 2);
    __hip_bfloat16* wqkvB = (__hip_bfloat16*)alloc((size_t)3 * C_CH * C_CH * 2);
    __hip_bfloat16* woutB = (__hip_bfloat16*)alloc((size_t)C_CH * C_CH * 2);
    __hip_bfloat16* qk    = (__hip_bfloat16*)alloc((size_t)BATCH * 2 * C_CH * HW * 2);
    __hip_bfloat16* vT    = (__hip_bfloat16*)alloc((size_t)BATCH * HW * C_CH * 2);
    __hip_bfloat16* att   = (__hip_bfloat16*)alloc((size_t)BATCH * C_CH * C_CH * 2);
    __hip_bfloat16* outT  = (__hip_bfloat16*)alloc((size_t)BATCH * HW * C_CH * 2);
    float* stats          = (float*)alloc((size_t)BATCH * NG * 2 * 4);

    // 1) cast weights to bf16
    {
        int n4 = (3 * C_CH * C_CH) / 4;
        cast_bf16_kernel<<<(n4 + 255) / 256, 256, 0, stream>>>(
            (const float4*)w_qkv, (ushort4*)wqkvB, n4);
        int n4b = (C_CH * C_CH) / 4;
        cast_bf16_kernel<<<(n4b + 255) / 256, 256, 0, stream>>>(
            (const float4*)w_out, (ushort4*)woutB, n4b);
    }
    // 2) GroupNorm stats + normalize/transpose
    gn_stats_kernel<<<BATCH * NG, 256, 0, stream>>>(x, stats);
    gn_norm_kernel<<<dim3(HW / 64, BATCH), 256, 0, stream>>>(x, stats, gamma, beta, xnT);

    // 3) GEMM1a: qk[b,o,p] o<1536  (M=1536,N=1024,K=768)
    gemm_nt_kernel<0><<<dim3(HW / 128, 1536 / 128, BATCH), 256, 0, stream>>>(
        wqkvB, 0, xnT, (long)HW * C_CH, qk, (long)2 * C_CH * HW, HW,
        C_CH, 1.0f, b_qkv, nullptr, nullptr, 0);

    // 4) GEMM1b: v_T[b,p,j] (M=1024,N=768,K=768)
    gemm_nt_kernel<0><<<dim3(C_CH / 128, HW / 128, BATCH), 256, 0, stream>>>(
        xnT, (long)HW * C_CH, wqkvB + (size_t)2 * C_CH * C_CH, 0, vT, (long)HW * C_CH, C_CH,
        C_CH, 1.0f, nullptr, b_qkv + 2 * C_CH, nullptr, 0);

    // 5) GEMM2: att[b,i,j] = q.k^T * hw^-0.5  (M=768,N=768,K=1024)
    gemm_nt_kernel<0><<<dim3(C_CH / 128, C_CH / 128, BATCH), 256, 0, stream>>>(
        qk, (long)2 * C_CH * HW, qk + (size_t)C_CH * HW, (long)2 * C_CH * HW,
        att, (long)C_CH * C_CH, C_CH,
        HW, 1.0f / 32.0f, nullptr, nullptr, nullptr, 0);

    // 6) softmax rows
    softmax_kernel<<<(BATCH * C_CH) / 4, 256, 0, stream>>>(att);

    // 7) GEMM3: out_T[b,p,i] = v_T . att^T  (M=1024,N=768,K=768)
    gemm_nt_kernel<0><<<dim3(C_CH / 128, HW / 128, BATCH), 256, 0, stream>>>(
        vT, (long)HW * C_CH, att, (long)C_CH * C_CH, outT, (long)HW * C_CH, C_CH,
        C_CH, 1.0f, nullptr, nullptr, nullptr, 0);

    // 8) GEMM4: out[b,o,p] = w_out . out_T^T + b_out + x  (M=768,N=1024,K=768), f32 out
    gemm_nt_kernel<1><<<dim3(HW / 128, C_CH / 128, BATCH), 256, 0, stream>>>(
        woutB, 0, outT, (long)HW * C_CH, (float*)d_out, (long)C_CH * HW, HW,
        C_CH, 1.0f, b_out, nullptr, x, (long)C_CH * HW);
}

// Round 3
// 360.800 us; speedup vs baseline: 1.0085x; 1.0085x over previous
//
#include <hip/hip_runtime.h>
#include <hip/hip_bf16.h>

#define HW 1024
#define C_CH 768
#define BATCH 16
#define NG 32
#define CPG 24
#define EPS 1e-5f

typedef __attribute__((ext_vector_type(8))) short bf16x8;
typedef __attribute__((ext_vector_type(4))) float f32x4;
typedef unsigned short u16;
typedef unsigned int u32;

typedef const __attribute__((address_space(1))) void* gas_ptr;
typedef __attribute__((address_space(3))) void* las_ptr;

__device__ __forceinline__ void load_lds16(const void* g, void* l) {
    __builtin_amdgcn_global_load_lds((gas_ptr)g, (las_ptr)l, 16, 0, 0);
}

__device__ __forceinline__ u16 f2bf(float f) {
    __hip_bfloat16 h = __float2bfloat16(f);
    return *(u16*)&h;
}
__device__ __forceinline__ float bf2f(u16 u) {
    return __uint_as_float(((u32)u) << 16);
}

// ---------------- cast f32 -> bf16 (vectorized x4) ----------------
__global__ __launch_bounds__(256) void cast_bf16_kernel(const float4* __restrict__ in,
                                                        ushort4* __restrict__ out, int n4) {
    int i = blockIdx.x * 256 + threadIdx.x;
    if (i >= n4) return;
    float4 v = in[i];
    ushort4 u;
    u.x = f2bf(v.x); u.y = f2bf(v.y); u.z = f2bf(v.z); u.w = f2bf(v.w);
    out[i] = u;
}

// ---------------- GroupNorm stats: one block per (b,g) ----------------
__global__ __launch_bounds__(256) void gn_stats_kernel(const float* __restrict__ x,
                                                       float* __restrict__ stats) {
    int bg = blockIdx.x;                       // b*NG + g
    const float4* p4 = (const float4*)(x + (size_t)bg * (CPG * HW));
    float s = 0.f, s2 = 0.f;
    for (int i = threadIdx.x; i < (CPG * HW) / 4; i += 256) {
        float4 v = p4[i];
        s  += v.x + v.y + v.z + v.w;
        s2 += v.x * v.x + v.y * v.y + v.z * v.z + v.w * v.w;
    }
    int lane = threadIdx.x & 63, wid = threadIdx.x >> 6;
    for (int off = 32; off; off >>= 1) {
        s  += __shfl_xor(s,  off, 64);
        s2 += __shfl_xor(s2, off, 64);
    }
    __shared__ float red[8];
    if (lane == 0) { red[wid * 2] = s; red[wid * 2 + 1] = s2; }
    __syncthreads();
    if (threadIdx.x == 0) {
        s = red[0] + red[2] + red[4] + red[6];
        s2 = red[1] + red[3] + red[5] + red[7];
        float mean = s / (float)(CPG * HW);
        float var  = s2 / (float)(CPG * HW) - mean * mean;
        stats[2 * bg]     = mean;
        stats[2 * bg + 1] = rsqrtf(var + EPS);
    }
}

// ------------- GroupNorm normalize + transpose -> xn_T [B, HW, C] bf16 -------------
__global__ __launch_bounds__(256) void gn_norm_kernel(const float* __restrict__ x,
                                                      const float* __restrict__ stats,
                                                      const float* __restrict__ gamma,
                                                      const float* __restrict__ beta,
                                                      __hip_bfloat16* __restrict__ xnT) {
    __shared__ float lds[64][65];
    int b  = blockIdx.y;
    int p0 = blockIdx.x * 64;
    int t = threadIdx.x;
    int lane = t & 63;
    int grp  = t >> 6;   // 0..3
    for (int cc = 0; cc < C_CH / 64; cc++) {
        int c0 = cc * 64;
        for (int i = 0; i < 16; i++) {
            int c = c0 + grp * 16 + i;
            float2 st = ((const float2*)stats)[b * NG + c / CPG];
            float ga = gamma[c], be = beta[c];
            float v = x[((size_t)b * C_CH + c) * HW + p0 + lane];
            lds[lane][grp * 16 + i] = (v - st.x) * st.y * ga + be;
        }
        __syncthreads();
        for (int i = 0; i < 16; i++) {
            int pp = grp * 16 + i;
            xnT[((size_t)b * HW + p0 + pp) * C_CH + c0 + lane] =
                __float2bfloat16(lds[pp][lane]);
        }
        __syncthreads();
    }
}

// ---------------- row softmax over att [rows][768] bf16, in place ----------------
__global__ __launch_bounds__(256) void softmax_kernel(__hip_bfloat16* __restrict__ att) {
    int row  = blockIdx.x * 4 + (threadIdx.x >> 6);
    int lane = threadIdx.x & 63;
    u16* p = (u16*)(att + (size_t)row * C_CH);
    float v[12];
    float m = -1e30f;
    for (int j = 0; j < 12; j++) {
        v[j] = bf2f(p[j * 64 + lane]);
        m = fmaxf(m, v[j]);
    }
    for (int off = 32; off; off >>= 1) m = fmaxf(m, __shfl_xor(m, off, 64));
    float s = 0.f;
    for (int j = 0; j < 12; j++) { v[j] = __expf(v[j] - m); s += v[j]; }
    for (int off = 32; off; off >>= 1) s += __shfl_xor(s, off, 64);
    float inv = 1.0f / s;
    for (int j = 0; j < 12; j++) p[j * 64 + lane] = f2bf(v[j] * inv);
}

// ---------------- NT GEMM: C[m,n] = scale * sum_k A[m,k]*B[n,k] (+bias/res) ----------------
// Tile 256(M) x 128(N), BK=64, 512 threads = 8 waves as 4M x 2N, wave tile 64x64.
// 3-buffer LDS ring with counted vmcnt: iter kt stages tile kt+2, computes tile kt,
// ends with s_waitcnt vmcnt(6) lgkmcnt(0) + s_barrier -> one K-tile (6 loads/thread)
// stays in flight across every barrier. Buffers are STATIC (unroll-by-3) so the
// compiler can disambiguate LDS aliasing and not insert vmcnt(0) drains.
// XOR-swizzled staging (phys chunk = logical ^ (row&7)) keeps ds_read_b128 conflict-free.
template<int OUT_F32>
__global__ __launch_bounds__(512, 2) void gemm_nt_kernel(
    const __hip_bfloat16* __restrict__ A, long sA,
    const __hip_bfloat16* __restrict__ B, long sB,
    void* __restrict__ Cout, long sC, int ldc,
    int K, float scale,
    const float* __restrict__ bias_row,
    const float* __restrict__ bias_col,
    const float* __restrict__ residual, long sR)
{
    __shared__ __hip_bfloat16 As[3][256 * 64];
    __shared__ __hip_bfloat16 Bs[3][128 * 64];
    const int t  = threadIdx.x;
    const int b  = blockIdx.z;
    const int m0 = blockIdx.y * 256;
    const int n0 = blockIdx.x * 128;
    const int lane = t & 63;
    const int wid  = t >> 6;
    const int wm = wid >> 1;      // 0..3 -> 64-row band
    const int wn = wid & 1;       // 0..1 -> 64-col band
    const int lrow = lane & 15, lk = lane >> 4;

    // staging geometry: 16B chunk c = l*512 + t; row = c>>3, phys chunk = t&7
    const int srow  = t >> 3;                         // 0..63 (+ l*64)
    const int kphys = ((t & 7) ^ (srow & 7)) * 8;     // source k elem offset in [0,64)
    const __hip_bfloat16* aB0 = A + (size_t)b * sA + (size_t)(m0 + srow) * K + kphys;
    const __hip_bfloat16* bB0 = B + (size_t)b * sB + (size_t)(n0 + srow) * K + kphys;
    const int dstBase = (t & ~63) * 8;                // wave-uniform elem offset (+l*4096)

    f32x4 acc[4][4] = {};
    const int nk = K >> 6;

    auto stage = [&](__hip_bfloat16* as, __hip_bfloat16* bs, int kt) {
        const __hip_bfloat16* ak = aB0 + (size_t)kt * 64;
        const __hip_bfloat16* bk = bB0 + (size_t)kt * 64;
#pragma unroll
        for (int l = 0; l < 4; l++)
            load_lds16(ak + (size_t)l * 64 * K, as + dstBase + l * 4096);
#pragma unroll
        for (int l = 0; l < 2; l++)
            load_lds16(bk + (size_t)l * 64 * K, bs + dstBase + l * 4096);
    };

    auto compute = [&](const __hip_bfloat16* as, const __hip_bfloat16* bs) {
#pragma unroll
        for (int h = 0; h < 2; h++) {
            bf16x8 af[4], bfr[4];
            const int lc = h * 4 + lk;
#pragma unroll
            for (int i = 0; i < 4; i++) {
                int row = wm * 64 + i * 16 + lrow;
                af[i] = *(const bf16x8*)(as + row * 64 + (lc ^ (row & 7)) * 8);
            }
#pragma unroll
            for (int j = 0; j < 4; j++) {
                int col = wn * 64 + j * 16 + lrow;
                bfr[j] = *(const bf16x8*)(bs + col * 64 + (lc ^ (col & 7)) * 8);
            }
            __builtin_amdgcn_s_setprio(1);
#pragma unroll
            for (int i = 0; i < 4; i++)
#pragma unroll
                for (int j = 0; j < 4; j++)
                    acc[i][j] = __builtin_amdgcn_mfma_f32_16x16x32_bf16(
                        af[i], bfr[j], acc[i][j], 0, 0, 0);
            __builtin_amdgcn_s_setprio(0);
        }
    };

#define GSLOT(KT, CBUF, SBUF)                                                     \
    do {                                                                          \
        const int _kt = (KT);                                                     \
        const bool _st = (_kt + 2 < nk);                                          \
        if (_st) stage(As[SBUF], Bs[SBUF], _kt + 2);                              \
        compute(As[CBUF], Bs[CBUF]);                                              \
        if (_kt + 1 < nk) {                                                       \
            if (_st) { asm volatile("s_waitcnt vmcnt(6) lgkmcnt(0)" ::: "memory"); } \
            else     { asm volatile("s_waitcnt vmcnt(0) lgkmcnt(0)" ::: "memory"); } \
            __builtin_amdgcn_s_barrier();                                         \
        }                                                                         \
    } while (0)

    // prologue: tiles 0 and 1 in flight; wait for tile 0 (6 newest stay outstanding)
    stage(As[0], Bs[0], 0);
    stage(As[1], Bs[1], 1);
    asm volatile("s_waitcnt vmcnt(6)" ::: "memory");
    __builtin_amdgcn_s_barrier();

    int kt3 = 0;
    for (; kt3 + 3 <= nk; kt3 += 3) {
        GSLOT(kt3 + 0, 0, 2);
        GSLOT(kt3 + 1, 1, 0);
        GSLOT(kt3 + 2, 2, 1);
    }
    if (nk - kt3 == 1) {
        GSLOT(kt3, 0, 2);
    } else if (nk - kt3 == 2) {
        GSLOT(kt3 + 0, 0, 2);
        GSLOT(kt3 + 1, 1, 0);
    }
#undef GSLOT

    __hip_bfloat16* outB = (__hip_bfloat16*)Cout;
    float* outF = (float*)Cout;
#pragma unroll
    for (int i = 0; i < 4; i++)
#pragma unroll
        for (int j = 0; j < 4; j++) {
            int row = m0 + wm * 64 + i * 16 + lk * 4;
            int col = n0 + wn * 64 + j * 16 + lrow;
            f32x4 a = acc[i][j];
#pragma unroll
            for (int r = 0; r < 4; r++) {
                int rr = row + r;
                float v = a[r] * scale;
                if (bias_row) v += bias_row[rr];
                if (bias_col) v += bias_col[col];
                if (residual) v += residual[(size_t)b * sR + (size_t)rr * ldc + col];
                size_t off = (size_t)b * sC + (size_t)rr * ldc + col;
                if (OUT_F32) outF[off] = v;
                else         outB[off] = __float2bfloat16(v);
            }
        }
}

extern "C" void kernel_launch(void* const* d_in, const int* in_sizes, int n_in,
                              void* d_out, int out_size, void* d_ws, size_t ws_size,
                              hipStream_t stream) {
    const float* x     = (const float*)d_in[0];
    const float* gamma = (const float*)d_in[1];
    const float* beta  = (const float*)d_in[2];
    const float* w_qkv = (const float*)d_in[3];
    const float* b_qkv = (const float*)d_in[4];
    const float* w_out = (const float*)d_in[5];
    const float* b_out = (const float*)d_in[6];

    char* ws = (char*)d_ws;
    size_t off = 0;
    auto alloc = [&](size_t bytes) {
        void* p = ws + off;
        off += (bytes + 255) & ~(size_t)255;
        return p;
    };
    __hip_bfloat16* xnT   = (__hip_bfloat16*)alloc((size_t)BATCH * HW * C_CH * 2);
    __hip_bfloat16* wqkvB = (__hip_bfloat16*)alloc((size_t)3 * C_CH * C_CH * 2);
    __hip_bfloat16* woutB = (__hip_bfloat16*)alloc((size_t)C_CH * C_CH * 2);
    __hip_bfloat16* qk    = (__hip_bfloat16*)alloc((size_t)BATCH * 2 * C_CH * HW * 2);
    __hip_bfloat16* vT    = (__hip_bfloat16*)alloc((size_t)BATCH * HW * C_CH * 2);
    __hip_bfloat16* att   = (__hip_bfloat16*)alloc((size_t)BATCH * C_CH * C_CH * 2);
    __hip_bfloat16* outT  = (__hip_bfloat16*)alloc((size_t)BATCH * HW * C_CH * 2);
    float* stats          = (float*)alloc((size_t)BATCH * NG * 2 * 4);

    // 1) cast weights to bf16
    {
        int n4 = (3 * C_CH * C_CH) / 4;
        cast_bf16_kernel<<<(n4 + 255) / 256, 256, 0, stream>>>(
            (const float4*)w_qkv, (ushort4*)wqkvB, n4);
        int n4b = (C_CH * C_CH) / 4;
        cast_bf16_kernel<<<(n4b + 255) / 256, 256, 0, stream>>>(
            (const float4*)w_out, (ushort4*)woutB, n4b);
    }
    // 2) GroupNorm stats + normalize/transpose
    gn_stats_kernel<<<BATCH * NG, 256, 0, stream>>>(x, stats);
    gn_norm_kernel<<<dim3(HW / 64, BATCH), 256, 0, stream>>>(x, stats, gamma, beta, xnT);

    // 3) GEMM1a: qk[b,o,p] o<1536  (M=1536,N=1024,K=768)
    gemm_nt_kernel<0><<<dim3(HW / 128, 1536 / 256, BATCH), 512, 0, stream>>>(
        wqkvB, 0, xnT, (long)HW * C_CH, qk, (long)2 * C_CH * HW, HW,
        C_CH, 1.0f, b_qkv, nullptr, nullptr, 0);

    // 4) GEMM1b: v_T[b,p,j] (M=1024,N=768,K=768)
    gemm_nt_kernel<0><<<dim3(C_CH / 128, HW / 256, BATCH), 512, 0, stream>>>(
        xnT, (long)HW * C_CH, wqkvB + (size_t)2 * C_CH * C_CH, 0, vT, (long)HW * C_CH, C_CH,
        C_CH, 1.0f, nullptr, b_qkv + 2 * C_CH, nullptr, 0);

    // 5) GEMM2: att[b,i,j] = q.k^T * hw^-0.5  (M=768,N=768,K=1024)
    gemm_nt_kernel<0><<<dim3(C_CH / 128, C_CH / 256, BATCH), 512, 0, stream>>>(
        qk, (long)2 * C_CH * HW, qk + (size_t)C_CH * HW, (long)2 * C_CH * HW,
        att, (long)C_CH * C_CH, C_CH,
        HW, 1.0f / 32.0f, nullptr, nullptr, nullptr, 0);

    // 6) softmax rows
    softmax_kernel<<<(BATCH * C_CH) / 4, 256, 0, stream>>>(att);

    // 7) GEMM3: out_T[b,p,i] = v_T . att^T  (M=1024,N=768,K=768)
    gemm_nt_kernel<0><<<dim3(C_CH / 128, HW / 256, BATCH), 512, 0, stream>>>(
        vT, (long)HW * C_CH, att, (long)C_CH * C_CH, outT, (long)HW * C_CH, C_CH,
        C_CH, 1.0f, nullptr, nullptr, nullptr, 0);

    // 8) GEMM4: out[b,o,p] = w_out . out_T^T + b_out + x  (M=768,N=1024,K=768), f32 out
    gemm_nt_kernel<1><<<dim3(HW / 128, C_CH / 256, BATCH), 512, 0, stream>>>(
        woutB, 0, outT, (long)HW * C_CH, (float*)d_out, (long)C_CH * HW, HW,
        C_CH, 1.0f, b_out, nullptr, x, (long)C_CH * HW);
}

// Round 4
// 342.365 us; speedup vs baseline: 1.0629x; 1.0538x over previous
//
#include <hip/hip_runtime.h>
#include <hip/hip_bf16.h>

#define HW 1024
#define C_CH 768
#define BATCH 16
#define NG 32
#define CPG 24
#define EPS 1e-5f

typedef __attribute__((ext_vector_type(8))) short bf16x8;
typedef __attribute__((ext_vector_type(4))) float f32x4;
typedef unsigned short u16;
typedef unsigned int u32;

typedef const __attribute__((address_space(1))) void* gas_ptr;
typedef __attribute__((address_space(3))) void* las_ptr;

__device__ __forceinline__ void load_lds16(const void* g, void* l) {
    __builtin_amdgcn_global_load_lds((gas_ptr)g, (las_ptr)l, 16, 0, 0);
}

__device__ __forceinline__ u16 f2bf(float f) {
    __hip_bfloat16 h = __float2bfloat16(f);
    return *(u16*)&h;
}
__device__ __forceinline__ float bf2f(u16 u) {
    return __uint_as_float(((u32)u) << 16);
}

// ---------------- cast f32 -> bf16 (vectorized x4) ----------------
__global__ __launch_bounds__(256) void cast_bf16_kernel(const float4* __restrict__ in,
                                                        ushort4* __restrict__ out, int n4) {
    int i = blockIdx.x * 256 + threadIdx.x;
    if (i >= n4) return;
    float4 v = in[i];
    ushort4 u;
    u.x = f2bf(v.x); u.y = f2bf(v.y); u.z = f2bf(v.z); u.w = f2bf(v.w);
    out[i] = u;
}

// ---------------- GroupNorm stats: one block per (b,g) ----------------
__global__ __launch_bounds__(256) void gn_stats_kernel(const float* __restrict__ x,
                                                       float* __restrict__ stats) {
    int bg = blockIdx.x;                       // b*NG + g
    const float4* p4 = (const float4*)(x + (size_t)bg * (CPG * HW));
    float s = 0.f, s2 = 0.f;
    for (int i = threadIdx.x; i < (CPG * HW) / 4; i += 256) {
        float4 v = p4[i];
        s  += v.x + v.y + v.z + v.w;
        s2 += v.x * v.x + v.y * v.y + v.z * v.z + v.w * v.w;
    }
    int lane = threadIdx.x & 63, wid = threadIdx.x >> 6;
    for (int off = 32; off; off >>= 1) {
        s  += __shfl_xor(s,  off, 64);
        s2 += __shfl_xor(s2, off, 64);
    }
    __shared__ float red[8];
    if (lane == 0) { red[wid * 2] = s; red[wid * 2 + 1] = s2; }
    __syncthreads();
    if (threadIdx.x == 0) {
        s = red[0] + red[2] + red[4] + red[6];
        s2 = red[1] + red[3] + red[5] + red[7];
        float mean = s / (float)(CPG * HW);
        float var  = s2 / (float)(CPG * HW) - mean * mean;
        stats[2 * bg]     = mean;
        stats[2 * bg + 1] = rsqrtf(var + EPS);
    }
}

// ------------- GroupNorm normalize + transpose -> xn_T [B, HW, C] bf16 -------------
__global__ __launch_bounds__(256) void gn_norm_kernel(const float* __restrict__ x,
                                                      const float* __restrict__ stats,
                                                      const float* __restrict__ gamma,
                                                      const float* __restrict__ beta,
                                                      __hip_bfloat16* __restrict__ xnT) {
    __shared__ float lds[64][65];
    int b  = blockIdx.y;
    int p0 = blockIdx.x * 64;
    int t = threadIdx.x;
    int lane = t & 63;
    int grp  = t >> 6;   // 0..3
    for (int cc = 0; cc < C_CH / 64; cc++) {
        int c0 = cc * 64;
        for (int i = 0; i < 16; i++) {
            int c = c0 + grp * 16 + i;
            float2 st = ((const float2*)stats)[b * NG + c / CPG];
            float ga = gamma[c], be = beta[c];
            float v = x[((size_t)b * C_CH + c) * HW + p0 + lane];
            lds[lane][grp * 16 + i] = (v - st.x) * st.y * ga + be;
        }
        __syncthreads();
        for (int i = 0; i < 16; i++) {
            int pp = grp * 16 + i;
            xnT[((size_t)b * HW + p0 + pp) * C_CH + c0 + lane] =
                __float2bfloat16(lds[pp][lane]);
        }
        __syncthreads();
    }
}

// ---------------- row softmax over att [rows][768] bf16, in place ----------------
__global__ __launch_bounds__(256) void softmax_kernel(__hip_bfloat16* __restrict__ att) {
    int row  = blockIdx.x * 4 + (threadIdx.x >> 6);
    int lane = threadIdx.x & 63;
    u16* p = (u16*)(att + (size_t)row * C_CH);
    float v[12];
    float m = -1e30f;
    for (int j = 0; j < 12; j++) {
        v[j] = bf2f(p[j * 64 + lane]);
        m = fmaxf(m, v[j]);
    }
    for (int off = 32; off; off >>= 1) m = fmaxf(m, __shfl_xor(m, off, 64));
    float s = 0.f;
    for (int j = 0; j < 12; j++) { v[j] = __expf(v[j] - m); s += v[j]; }
    for (int off = 32; off; off >>= 1) s += __shfl_xor(s, off, 64);
    float inv = 1.0f / s;
    for (int j = 0; j < 12; j++) p[j * 64 + lane] = f2bf(v[j] * inv);
}

// ======================= NT GEMM, 256x256 tile, 8-phase schedule =======================
// C[m,n] = scale * sum_k A[m,k]*B[n,k] (+bias_row[m] +bias_col[n] +residual)
// A: [M x K] row-major (stride K), B: [N x K] row-major. 512 threads = 8 waves (2M x 4N),
// wave tile 128x64, acc = f32x4[8][4]. BK=64 (2 MFMA k-steps of 32).
// LDS: 2 dbuf x (A[256][64] + B[256][64]) bf16 = 128 KB, XOR-swizzled 16B chunks
// (phys = logical ^ (row&7)) -> conflict-free ds_read_b128 (verified 0 conflicts).
//
// Per K-tile t (buf d=t&1), 4 phases, each: {ds_reads; stage; s_barrier; lgkmcnt(0);
// setprio(1); 16 MFMA; setprio(0); s_barrier}:
//  ph0: rd A[i0-7]@k0 + B[j0,j1]@k0;   stage B-half0(t+1) -> buf d^1
//  ph1: rd B[j2,j3]@k0;                stage B-half1(t+1) -> buf d^1
//  ph2: rd A[i0-7]@k1 + B[j0,j1]@k1;   (no stage)
//  ph3: rd B[j2,j3]@k1;                stage A-half0+1(t+2) -> buf d (A slots dead after ph2)
//       then vmcnt(4) (keep next A in flight; vmcnt(0) only at tail) before the barrier.
// Slot-liveness ledger: A-slots of buf d last read at ph2(t) -> restage ph3(t) OK (barrier
// between). B-slots of buf d^1 last read ph3(t-1) -> restage ph0/ph1(t) OK. Boundary
// vmcnt(4) leaves only A(t+2)'s 4 loads outstanding => tile t+1 fully landed. Prologue:
// stage tile0 (8) + A(1) (4), vmcnt(4), barrier.
template<int OUT_F32>
__global__ __launch_bounds__(512, 2) void gemm_nt_kernel(
    const __hip_bfloat16* __restrict__ A, long sA,
    const __hip_bfloat16* __restrict__ B, long sB,
    void* __restrict__ Cout, long sC, int ldc,
    int K, float scale,
    const float* __restrict__ bias_row,
    const float* __restrict__ bias_col,
    const float* __restrict__ residual, long sR)
{
    __shared__ __hip_bfloat16 As[2][256 * 64];
    __shared__ __hip_bfloat16 Bs[2][256 * 64];
    const int t  = threadIdx.x;
    const int bz = blockIdx.z;
    const int m0 = blockIdx.y * 256;
    const int n0 = blockIdx.x * 256;
    const int lane = t & 63;
    const int wid  = t >> 6;
    const int wm = wid >> 2;      // 0..1 -> 128-row band
    const int wn = wid & 3;       // 0..3 -> 64-col band
    const int lrow = lane & 15, lk = lane >> 4;

    // staging geometry: 16B chunk c = l*512 + t; local row = c>>3, phys chunk = t&7
    const int srow  = t >> 3;                         // 0..63 (l adds 64)
    const int kphys = ((t & 7) ^ (srow & 7)) * 8;     // source k elem offset in [0,64)
    const int dstW  = (t & ~63) * 8;                  // wave-uniform elem offset

    const __hip_bfloat16* Abase = A + (size_t)bz * sA + (size_t)m0 * K;
    const __hip_bfloat16* Bbase = B + (size_t)bz * sB + (size_t)n0 * K;

    const int nk = K >> 6;

    auto stageA = [&](int d, int h, int kt) {   // A-half h (rows h*128..+127) of tile kt
        const __hip_bfloat16* src = Abase + (size_t)(h * 128 + srow) * K + kt * 64 + kphys;
        __hip_bfloat16* dst = &As[d][h * 8192 + dstW];
        load_lds16(src, dst);
        load_lds16(src + (size_t)64 * K, dst + 4096);
    };
    auto stageB = [&](int d, int h, int kt) {
        const __hip_bfloat16* src = Bbase + (size_t)(h * 128 + srow) * K + kt * 64 + kphys;
        __hip_bfloat16* dst = &Bs[d][h * 8192 + dstW];
        load_lds16(src, dst);
        load_lds16(src + (size_t)64 * K, dst + 4096);
    };

    f32x4 acc[8][4] = {};

    // ---- prologue: tile 0 complete-in-flight, A of tile 1 behind it ----
    stageA(0, 0, 0); stageA(0, 1, 0);
    stageB(0, 0, 0); stageB(0, 1, 0);
    stageA(1, 0, 1); stageA(1, 1, 1);
    asm volatile("s_waitcnt vmcnt(4)" ::: "memory");
    __builtin_amdgcn_s_barrier();

    for (int tk = 0; tk < nk; tk++) {
        const int d = tk & 1;
        const __hip_bfloat16* as = As[d];
        const __hip_bfloat16* bs = Bs[d];
        auto rdA = [&](int i, int ks) -> bf16x8 {
            int row = wm * 128 + i * 16 + lrow;
            int pc  = (ks * 4 + lk) ^ (row & 7);
            return *(const bf16x8*)(as + row * 64 + pc * 8);
        };
        auto rdB = [&](int j, int ks) -> bf16x8 {
            int col = wn * 64 + j * 16 + lrow;
            int pc  = (ks * 4 + lk) ^ (col & 7);
            return *(const bf16x8*)(bs + col * 64 + pc * 8);
        };
        bf16x8 a[8], b0, b1, b2, b3;

        // ---------------- phase 0 ----------------
#pragma unroll
        for (int i = 0; i < 8; i++) a[i] = rdA(i, 0);
        b0 = rdB(0, 0); b1 = rdB(1, 0);
        if (tk + 1 < nk) stageB(d ^ 1, 0, tk + 1);
        __builtin_amdgcn_s_barrier();
        asm volatile("s_waitcnt lgkmcnt(0)" ::: "memory");
        __builtin_amdgcn_sched_barrier(0);
        __builtin_amdgcn_s_setprio(1);
#pragma unroll
        for (int i = 0; i < 8; i++) {
            acc[i][0] = __builtin_amdgcn_mfma_f32_16x16x32_bf16(a[i], b0, acc[i][0], 0, 0, 0);
            acc[i][1] = __builtin_amdgcn_mfma_f32_16x16x32_bf16(a[i], b1, acc[i][1], 0, 0, 0);
        }
        __builtin_amdgcn_s_setprio(0);
        __builtin_amdgcn_s_barrier();

        // ---------------- phase 1 ----------------
        b2 = rdB(2, 0); b3 = rdB(3, 0);
        if (tk + 1 < nk) stageB(d ^ 1, 1, tk + 1);
        __builtin_amdgcn_s_barrier();
        asm volatile("s_waitcnt lgkmcnt(0)" ::: "memory");
        __builtin_amdgcn_sched_barrier(0);
        __builtin_amdgcn_s_setprio(1);
#pragma unroll
        for (int i = 0; i < 8; i++) {
            acc[i][2] = __builtin_amdgcn_mfma_f32_16x16x32_bf16(a[i], b2, acc[i][2], 0, 0, 0);
            acc[i][3] = __builtin_amdgcn_mfma_f32_16x16x32_bf16(a[i], b3, acc[i][3], 0, 0, 0);
        }
        __builtin_amdgcn_s_setprio(0);
        __builtin_amdgcn_s_barrier();

        // ---------------- phase 2 ----------------
#pragma unroll
        for (int i = 0; i < 8; i++) a[i] = rdA(i, 1);
        b0 = rdB(0, 1); b1 = rdB(1, 1);
        __builtin_amdgcn_s_barrier();
        asm volatile("s_waitcnt lgkmcnt(0)" ::: "memory");
        __builtin_amdgcn_sched_barrier(0);
        __builtin_amdgcn_s_setprio(1);
#pragma unroll
        for (int i = 0; i < 8; i++) {
            acc[i][0] = __builtin_amdgcn_mfma_f32_16x16x32_bf16(a[i], b0, acc[i][0], 0, 0, 0);
            acc[i][1] = __builtin_amdgcn_mfma_f32_16x16x32_bf16(a[i], b1, acc[i][1], 0, 0, 0);
        }
        __builtin_amdgcn_s_setprio(0);
        __builtin_amdgcn_s_barrier();

        // ---------------- phase 3 ----------------
        b2 = rdB(2, 1); b3 = rdB(3, 1);
        if (tk + 2 < nk) { stageA(d, 0, tk + 2); stageA(d, 1, tk + 2); }
        if (tk < nk - 2) { asm volatile("s_waitcnt vmcnt(4)" ::: "memory"); }
        else             { asm volatile("s_waitcnt vmcnt(0)" ::: "memory"); }
        __builtin_amdgcn_s_barrier();
        asm volatile("s_waitcnt lgkmcnt(0)" ::: "memory");
        __builtin_amdgcn_sched_barrier(0);
        __builtin_amdgcn_s_setprio(1);
#pragma unroll
        for (int i = 0; i < 8; i++) {
            acc[i][2] = __builtin_amdgcn_mfma_f32_16x16x32_bf16(a[i], b2, acc[i][2], 0, 0, 0);
            acc[i][3] = __builtin_amdgcn_mfma_f32_16x16x32_bf16(a[i], b3, acc[i][3], 0, 0, 0);
        }
        __builtin_amdgcn_s_setprio(0);
        __builtin_amdgcn_s_barrier();
    }

    // ---- epilogue ----
    __hip_bfloat16* outB = (__hip_bfloat16*)Cout;
    float* outF = (float*)Cout;
#pragma unroll
    for (int i = 0; i < 8; i++)
#pragma unroll
        for (int j = 0; j < 4; j++) {
            int row = m0 + wm * 128 + i * 16 + lk * 4;
            int col = n0 + wn * 64 + j * 16 + lrow;
            f32x4 av = acc[i][j];
#pragma unroll
            for (int r = 0; r < 4; r++) {
                int rr = row + r;
                float v = av[r] * scale;
                if (bias_row) v += bias_row[rr];
                if (bias_col) v += bias_col[col];
                if (residual) v += residual[(size_t)bz * sR + (size_t)rr * ldc + col];
                size_t off = (size_t)bz * sC + (size_t)rr * ldc + col;
                if (OUT_F32) outF[off] = v;
                else         outB[off] = __float2bfloat16(v);
            }
        }
}

extern "C" void kernel_launch(void* const* d_in, const int* in_sizes, int n_in,
                              void* d_out, int out_size, void* d_ws, size_t ws_size,
                              hipStream_t stream) {
    const float* x     = (const float*)d_in[0];
    const float* gamma = (const float*)d_in[1];
    const float* beta  = (const float*)d_in[2];
    const float* w_qkv = (const float*)d_in[3];
    const float* b_qkv = (const float*)d_in[4];
    const float* w_out = (const float*)d_in[5];
    const float* b_out = (const float*)d_in[6];

    char* ws = (char*)d_ws;
    size_t off = 0;
    auto alloc = [&](size_t bytes) {
        void* p = ws + off;
        off += (bytes + 255) & ~(size_t)255;
        return p;
    };
    __hip_bfloat16* xnT   = (__hip_bfloat16*)alloc((size_t)BATCH * HW * C_CH * 2);
    __hip_bfloat16* wqkvB = (__hip_bfloat16*)alloc((size_t)3 * C_CH * C_CH * 2);
    __hip_bfloat16* woutB = (__hip_bfloat16*)alloc((size_t)C_CH * C_CH * 2);
    __hip_bfloat16* qk    = (__hip_bfloat16*)alloc((size_t)BATCH * 2 * C_CH * HW * 2);
    __hip_bfloat16* vT    = (__hip_bfloat16*)alloc((size_t)BATCH * HW * C_CH * 2);
    __hip_bfloat16* att   = (__hip_bfloat16*)alloc((size_t)BATCH * C_CH * C_CH * 2);
    __hip_bfloat16* outT  = (__hip_bfloat16*)alloc((size_t)BATCH * HW * C_CH * 2);
    float* stats          = (float*)alloc((size_t)BATCH * NG * 2 * 4);

    // 1) cast weights to bf16
    {
        int n4 = (3 * C_CH * C_CH) / 4;
        cast_bf16_kernel<<<(n4 + 255) / 256, 256, 0, stream>>>(
            (const float4*)w_qkv, (ushort4*)wqkvB, n4);
        int n4b = (C_CH * C_CH) / 4;
        cast_bf16_kernel<<<(n4b + 255) / 256, 256, 0, stream>>>(
            (const float4*)w_out, (ushort4*)woutB, n4b);
    }
    // 2) GroupNorm stats + normalize/transpose
    gn_stats_kernel<<<BATCH * NG, 256, 0, stream>>>(x, stats);
    gn_norm_kernel<<<dim3(HW / 64, BATCH), 256, 0, stream>>>(x, stats, gamma, beta, xnT);

    // 3) GEMM1a: qk[b,o,p] o<1536  (M=1536,N=1024,K=768)
    gemm_nt_kernel<0><<<dim3(HW / 256, 1536 / 256, BATCH), 512, 0, stream>>>(
        wqkvB, 0, xnT, (long)HW * C_CH, qk, (long)2 * C_CH * HW, HW,
        C_CH, 1.0f, b_qkv, nullptr, nullptr, 0);

    // 4) GEMM1b: v_T[b,p,j] (M=1024,N=768,K=768)
    gemm_nt_kernel<0><<<dim3(C_CH / 256, HW / 256, BATCH), 512, 0, stream>>>(
        xnT, (long)HW * C_CH, wqkvB + (size_t)2 * C_CH * C_CH, 0, vT, (long)HW * C_CH, C_CH,
        C_CH, 1.0f, nullptr, b_qkv + 2 * C_CH, nullptr, 0);

    // 5) GEMM2: att[b,i,j] = q.k^T * hw^-0.5  (M=768,N=768,K=1024)
    gemm_nt_kernel<0><<<dim3(C_CH / 256, C_CH / 256, BATCH), 512, 0, stream>>>(
        qk, (long)2 * C_CH * HW, qk + (size_t)C_CH * HW, (long)2 * C_CH * HW,
        att, (long)C_CH * C_CH, C_CH,
        HW, 1.0f / 32.0f, nullptr, nullptr, nullptr, 0);

    // 6) softmax rows
    softmax_kernel<<<(BATCH * C_CH) / 4, 256, 0, stream>>>(att);

    // 7) GEMM3: out_T[b,p,i] = v_T . att^T  (M=1024,N=768,K=768)
    gemm_nt_kernel<0><<<dim3(C_CH / 256, HW / 256, BATCH), 512, 0, stream>>>(
        vT, (long)HW * C_CH, att, (long)C_CH * C_CH, outT, (long)HW * C_CH, C_CH,
        C_CH, 1.0f, nullptr, nullptr, nullptr, 0);

    // 8) GEMM4: out[b,o,p] = w_out . out_T^T + b_out + x  (M=768,N=1024,K=768), f32 out
    gemm_nt_kernel<1><<<dim3(HW / 256, C_CH / 256, BATCH), 512, 0, stream>>>(
        woutB, 0, outT, (long)HW * C_CH, (float*)d_out, (long)C_CH * HW, HW,
        C_CH, 1.0f, b_out, nullptr, x, (long)C_CH * HW);
}

// Round 5
// 315.753 us; speedup vs baseline: 1.1524x; 1.0843x over previous
//
#include <hip/hip_runtime.h>
#include <hip/hip_bf16.h>

#define HW 1024
#define C_CH 768
#define BATCH 16
#define NG 32
#define CPG 24
#define EPS 1e-5f

typedef __attribute__((ext_vector_type(8))) short bf16x8;
typedef __attribute__((ext_vector_type(4))) float f32x4;
typedef unsigned short u16;
typedef unsigned int u32;

typedef const __attribute__((address_space(1))) void* gas_ptr;
typedef __attribute__((address_space(3))) void* las_ptr;

__device__ __forceinline__ void load_lds16(const void* g, void* l) {
    __builtin_amdgcn_global_load_lds((gas_ptr)g, (las_ptr)l, 16, 0, 0);
}

__device__ __forceinline__ u16 f2bf(float f) {
    __hip_bfloat16 h = __float2bfloat16(f);
    return *(u16*)&h;
}
__device__ __forceinline__ float bf2f(u16 u) {
    return __uint_as_float(((u32)u) << 16);
}

// ---------------- cast f32 -> bf16 (vectorized x4) ----------------
__global__ __launch_bounds__(256) void cast_bf16_kernel(const float4* __restrict__ in,
                                                        ushort4* __restrict__ out, int n4) {
    int i = blockIdx.x * 256 + threadIdx.x;
    if (i >= n4) return;
    float4 v = in[i];
    ushort4 u;
    u.x = f2bf(v.x); u.y = f2bf(v.y); u.z = f2bf(v.z); u.w = f2bf(v.w);
    out[i] = u;
}

// ---------------- GroupNorm stats: one block per (b,g) ----------------
__global__ __launch_bounds__(256) void gn_stats_kernel(const float* __restrict__ x,
                                                       float* __restrict__ stats) {
    int bg = blockIdx.x;                       // b*NG + g
    const float4* p4 = (const float4*)(x + (size_t)bg * (CPG * HW));
    float s = 0.f, s2 = 0.f;
    for (int i = threadIdx.x; i < (CPG * HW) / 4; i += 256) {
        float4 v = p4[i];
        s  += v.x + v.y + v.z + v.w;
        s2 += v.x * v.x + v.y * v.y + v.z * v.z + v.w * v.w;
    }
    int lane = threadIdx.x & 63, wid = threadIdx.x >> 6;
    for (int off = 32; off; off >>= 1) {
        s  += __shfl_xor(s,  off, 64);
        s2 += __shfl_xor(s2, off, 64);
    }
    __shared__ float red[8];
    if (lane == 0) { red[wid * 2] = s; red[wid * 2 + 1] = s2; }
    __syncthreads();
    if (threadIdx.x == 0) {
        s = red[0] + red[2] + red[4] + red[6];
        s2 = red[1] + red[3] + red[5] + red[7];
        float mean = s / (float)(CPG * HW);
        float var  = s2 / (float)(CPG * HW) - mean * mean;
        stats[2 * bg]     = mean;
        stats[2 * bg + 1] = rsqrtf(var + EPS);
    }
}

// ------------- GroupNorm normalize + transpose -> xn_T [B, HW, C] bf16 -------------
__global__ __launch_bounds__(256) void gn_norm_kernel(const float* __restrict__ x,
                                                      const float* __restrict__ stats,
                                                      const float* __restrict__ gamma,
                                                      const float* __restrict__ beta,
                                                      __hip_bfloat16* __restrict__ xnT) {
    __shared__ float lds[64][65];
    int b  = blockIdx.y;
    int p0 = blockIdx.x * 64;
    int t = threadIdx.x;
    int lane = t & 63;
    int grp  = t >> 6;   // 0..3
    for (int cc = 0; cc < C_CH / 64; cc++) {
        int c0 = cc * 64;
        for (int i = 0; i < 16; i++) {
            int c = c0 + grp * 16 + i;
            float2 st = ((const float2*)stats)[b * NG + c / CPG];
            float ga = gamma[c], be = beta[c];
            float v = x[((size_t)b * C_CH + c) * HW + p0 + lane];
            lds[lane][grp * 16 + i] = (v - st.x) * st.y * ga + be;
        }
        __syncthreads();
        for (int i = 0; i < 16; i++) {
            int pp = grp * 16 + i;
            xnT[((size_t)b * HW + p0 + pp) * C_CH + c0 + lane] =
                __float2bfloat16(lds[pp][lane]);
        }
        __syncthreads();
    }
}

// ---------------- row softmax over att [rows][768] bf16, in place ----------------
__global__ __launch_bounds__(256) void softmax_kernel(__hip_bfloat16* __restrict__ att) {
    int row  = blockIdx.x * 4 + (threadIdx.x >> 6);
    int lane = threadIdx.x & 63;
    u16* p = (u16*)(att + (size_t)row * C_CH);
    float v[12];
    float m = -1e30f;
    for (int j = 0; j < 12; j++) {
        v[j] = bf2f(p[j * 64 + lane]);
        m = fmaxf(m, v[j]);
    }
    for (int off = 32; off; off >>= 1) m = fmaxf(m, __shfl_xor(m, off, 64));
    float s = 0.f;
    for (int j = 0; j < 12; j++) { v[j] = __expf(v[j] - m); s += v[j]; }
    for (int off = 32; off; off >>= 1) s += __shfl_xor(s, off, 64);
    float inv = 1.0f / s;
    for (int j = 0; j < 12; j++) p[j * 64 + lane] = f2bf(v[j] * inv);
}

// ================= NT GEMM: 128x128 tile, BK=32, ring-of-3 LDS, counted vmcnt =================
// C[m,n] = scale * sum_k A[m,k]*B[n,k] (+bias_row[m] +bias_col[n] +residual)
// A: [M x K] row-major, B: [N x K] row-major. 256 threads = 4 waves (2M x 2N), wave tile 64x64.
// LDS = 3 bufs x (A[128][32] + B[128][32]) bf16 = 48 KB -> 3 blocks/CU co-resident (TLP like
// R1) PLUS 2-tile lookahead per block. Per K-step t: stage tile t+2 into slot (t+2)%3
// (4 global_load_lds), ds_read+16 MFMA on slot t%3, then s_waitcnt vmcnt(4) lgkmcnt(0) +
// s_barrier -- tile t+2's 4 loads stay in flight across the barrier; tile t+1 is guaranteed
// landed. Slots are compile-time constants (unroll-by-3) so no alias-driven drains.
// Ledger: slot (t+2)%3 restaged at step t was last ds_read at step t-1 (barrier between).
// Swizzle: 32-elem rows = 4x16B chunks; phys chunk = logical ^ (row&3); read side uses
// lk ^ (row&3). 64 lanes (16 rows x 4 chunks) -> exactly 2-way bank aliasing (free, m136).
template<int OUT_F32>
__global__ __launch_bounds__(256, 3) void gemm_nt_kernel(
    const __hip_bfloat16* __restrict__ A, long sA,
    const __hip_bfloat16* __restrict__ B, long sB,
    void* __restrict__ Cout, long sC, int ldc,
    int K, float scale,
    const float* __restrict__ bias_row,
    const float* __restrict__ bias_col,
    const float* __restrict__ residual, long sR)
{
    __shared__ __hip_bfloat16 As[3][128 * 32];
    __shared__ __hip_bfloat16 Bs[3][128 * 32];
    const int t  = threadIdx.x;
    const int bz = blockIdx.z;
    const int m0 = blockIdx.y * 128;
    const int n0 = blockIdx.x * 128;
    const int lane = t & 63;
    const int wid  = t >> 6;
    const int wm = wid >> 1, wn = wid & 1;          // 2x2 waves, 64x64 each
    const int lrow = lane & 15, lk = lane >> 4;     // frag row / k-chunk

    // staging: chunk ci = l*256 + t (l=0,1); row = ci>>2 = l*64 + (t>>2); log chunk = t&3
    const int srow0 = t >> 2;                       // row for l=0 (l=1 adds 64; 64%4==0)
    const int kph   = ((t & 3) ^ (srow0 & 3)) * 8;  // swizzled source k-elem offset [0,32)
    const int dstB  = (t & ~63) * 8;                // wave-uniform LDS elem offset (+l*2048)

    const __hip_bfloat16* aB0 = A + (size_t)bz * sA + (size_t)(m0 + srow0) * K + kph;
    const __hip_bfloat16* bB0 = B + (size_t)bz * sB + (size_t)(n0 + srow0) * K + kph;

    f32x4 acc[4][4] = {};
    const int nk = K >> 5;                          // BK=32

    auto stage = [&](__hip_bfloat16* as, __hip_bfloat16* bs, int kt) {
        const __hip_bfloat16* ak = aB0 + (size_t)kt * 32;
        const __hip_bfloat16* bk = bB0 + (size_t)kt * 32;
        load_lds16(ak,                  as + dstB);
        load_lds16(ak + (size_t)64 * K, as + dstB + 2048);
        load_lds16(bk,                  bs + dstB);
        load_lds16(bk + (size_t)64 * K, bs + dstB + 2048);
    };

    auto compute = [&](const __hip_bfloat16* as, const __hip_bfloat16* bs) {
        bf16x8 af[4], bfr[4];
#pragma unroll
        for (int i = 0; i < 4; i++) {
            int row = wm * 64 + i * 16 + lrow;
            af[i] = *(const bf16x8*)(as + row * 32 + (lk ^ (row & 3)) * 8);
        }
#pragma unroll
        for (int j = 0; j < 4; j++) {
            int col = wn * 64 + j * 16 + lrow;
            bfr[j] = *(const bf16x8*)(bs + col * 32 + (lk ^ (col & 3)) * 8);
        }
#pragma unroll
        for (int i = 0; i < 4; i++)
#pragma unroll
            for (int j = 0; j < 4; j++)
                acc[i][j] = __builtin_amdgcn_mfma_f32_16x16x32_bf16(
                    af[i], bfr[j], acc[i][j], 0, 0, 0);
    };

#define GSLOT(KT, CBUF, SBUF)                                                        \
    do {                                                                             \
        const int _kt = (KT);                                                        \
        const bool _st = (_kt + 2 < nk);                                             \
        if (_st) stage(As[SBUF], Bs[SBUF], _kt + 2);                                 \
        compute(As[CBUF], Bs[CBUF]);                                                 \
        if (_kt + 1 < nk) {                                                          \
            if (_st) { asm volatile("s_waitcnt vmcnt(4) lgkmcnt(0)" ::: "memory"); } \
            else     { asm volatile("s_waitcnt vmcnt(0) lgkmcnt(0)" ::: "memory"); } \
            __builtin_amdgcn_s_barrier();                                            \
        }                                                                            \
    } while (0)

    // prologue: tiles 0 and 1 issued; wait tile 0 landed (tile 1's 4 stay in flight)
    stage(As[0], Bs[0], 0);
    stage(As[1], Bs[1], 1);
    asm volatile("s_waitcnt vmcnt(4)" ::: "memory");
    __builtin_amdgcn_s_barrier();

    int kt3 = 0;
    for (; kt3 + 3 <= nk; kt3 += 3) {
        GSLOT(kt3 + 0, 0, 2);
        GSLOT(kt3 + 1, 1, 0);
        GSLOT(kt3 + 2, 2, 1);
    }
    if (nk - kt3 == 1) {
        GSLOT(kt3, 0, 2);
    } else if (nk - kt3 == 2) {
        GSLOT(kt3 + 0, 0, 2);
        GSLOT(kt3 + 1, 1, 0);
    }
#undef GSLOT

    __hip_bfloat16* outB = (__hip_bfloat16*)Cout;
    float* outF = (float*)Cout;
#pragma unroll
    for (int i = 0; i < 4; i++)
#pragma unroll
        for (int j = 0; j < 4; j++) {
            int row = m0 + wm * 64 + i * 16 + lk * 4;
            int col = n0 + wn * 64 + j * 16 + lrow;
            f32x4 a = acc[i][j];
#pragma unroll
            for (int r = 0; r < 4; r++) {
                int rr = row + r;
                float v = a[r] * scale;
                if (bias_row) v += bias_row[rr];
                if (bias_col) v += bias_col[col];
                if (residual) v += residual[(size_t)bz * sR + (size_t)rr * ldc + col];
                size_t off = (size_t)bz * sC + (size_t)rr * ldc + col;
                if (OUT_F32) outF[off] = v;
                else         outB[off] = __float2bfloat16(v);
            }
        }
}

extern "C" void kernel_launch(void* const* d_in, const int* in_sizes, int n_in,
                              void* d_out, int out_size, void* d_ws, size_t ws_size,
                              hipStream_t stream) {
    const float* x     = (const float*)d_in[0];
    const float* gamma = (const float*)d_in[1];
    const float* beta  = (const float*)d_in[2];
    const float* w_qkv = (const float*)d_in[3];
    const float* b_qkv = (const float*)d_in[4];
    const float* w_out = (const float*)d_in[5];
    const float* b_out = (const float*)d_in[6];

    char* ws = (char*)d_ws;
    size_t off = 0;
    auto alloc = [&](size_t bytes) {
        void* p = ws + off;
        off += (bytes + 255) & ~(size_t)255;
        return p;
    };
    __hip_bfloat16* xnT   = (__hip_bfloat16*)alloc((size_t)BATCH * HW * C_CH * 2);
    __hip_bfloat16* wqkvB = (__hip_bfloat16*)alloc((size_t)3 * C_CH * C_CH * 2);
    __hip_bfloat16* woutB = (__hip_bfloat16*)alloc((size_t)C_CH * C_CH * 2);
    __hip_bfloat16* qk    = (__hip_bfloat16*)alloc((size_t)BATCH * 2 * C_CH * HW * 2);
    __hip_bfloat16* vT    = (__hip_bfloat16*)alloc((size_t)BATCH * HW * C_CH * 2);
    __hip_bfloat16* att   = (__hip_bfloat16*)alloc((size_t)BATCH * C_CH * C_CH * 2);
    __hip_bfloat16* outT  = (__hip_bfloat16*)alloc((size_t)BATCH * HW * C_CH * 2);
    float* stats          = (float*)alloc((size_t)BATCH * NG * 2 * 4);

    // 1) cast weights to bf16
    {
        int n4 = (3 * C_CH * C_CH) / 4;
        cast_bf16_kernel<<<(n4 + 255) / 256, 256, 0, stream>>>(
            (const float4*)w_qkv, (ushort4*)wqkvB, n4);
        int n4b = (C_CH * C_CH) / 4;
        cast_bf16_kernel<<<(n4b + 255) / 256, 256, 0, stream>>>(
            (const float4*)w_out, (ushort4*)woutB, n4b);
    }
    // 2) GroupNorm stats + normalize/transpose
    gn_stats_kernel<<<BATCH * NG, 256, 0, stream>>>(x, stats);
    gn_norm_kernel<<<dim3(HW / 64, BATCH), 256, 0, stream>>>(x, stats, gamma, beta, xnT);

    // 3) GEMM1a: qk[b,o,p] o<1536  (M=1536,N=1024,K=768)
    gemm_nt_kernel<0><<<dim3(HW / 128, 1536 / 128, BATCH), 256, 0, stream>>>(
        wqkvB, 0, xnT, (long)HW * C_CH, qk, (long)2 * C_CH * HW, HW,
        C_CH, 1.0f, b_qkv, nullptr, nullptr, 0);

    // 4) GEMM1b: v_T[b,p,j] (M=1024,N=768,K=768)
    gemm_nt_kernel<0><<<dim3(C_CH / 128, HW / 128, BATCH), 256, 0, stream>>>(
        xnT, (long)HW * C_CH, wqkvB + (size_t)2 * C_CH * C_CH, 0, vT, (long)HW * C_CH, C_CH,
        C_CH, 1.0f, nullptr, b_qkv + 2 * C_CH, nullptr, 0);

    // 5) GEMM2: att[b,i,j] = q.k^T * hw^-0.5  (M=768,N=768,K=1024)
    gemm_nt_kernel<0><<<dim3(C_CH / 128, C_CH / 128, BATCH), 256, 0, stream>>>(
        qk, (long)2 * C_CH * HW, qk + (size_t)C_CH * HW, (long)2 * C_CH * HW,
        att, (long)C_CH * C_CH, C_CH,
        HW, 1.0f / 32.0f, nullptr, nullptr, nullptr, 0);

    // 6) softmax rows
    softmax_kernel<<<(BATCH * C_CH) / 4, 256, 0, stream>>>(att);

    // 7) GEMM3: out_T[b,p,i] = v_T . att^T  (M=1024,N=768,K=768)
    gemm_nt_kernel<0><<<dim3(C_CH / 128, HW / 128, BATCH), 256, 0, stream>>>(
        vT, (long)HW * C_CH, att, (long)C_CH * C_CH, outT, (long)HW * C_CH, C_CH,
        C_CH, 1.0f, nullptr, nullptr, nullptr, 0);

    // 8) GEMM4: out[b,o,p] = w_out . out_T^T + b_out + x  (M=768,N=1024,K=768), f32 out
    gemm_nt_kernel<1><<<dim3(HW / 128, C_CH / 128, BATCH), 256, 0, stream>>>(
        woutB, 0, outT, (long)HW * C_CH, (float*)d_out, (long)C_CH * HW, HW,
        C_CH, 1.0f, b_out, nullptr, x, (long)C_CH * HW);
}

// Round 6
// 236.508 us; speedup vs baseline: 1.5386x; 1.3351x over previous
//
#include <hip/hip_runtime.h>
#include <hip/hip_bf16.h>

#define HW 1024
#define C_CH 768
#define BATCH 16
#define NG 32
#define CPG 24
#define EPS 1e-5f

typedef __attribute__((ext_vector_type(8))) short bf16x8;
typedef __attribute__((ext_vector_type(4))) float f32x4;
typedef unsigned short u16;
typedef unsigned int u32;

typedef const __attribute__((address_space(1))) void* gas_ptr;
typedef __attribute__((address_space(3))) void* las_ptr;

__device__ __forceinline__ void load_lds16(const void* g, void* l) {
    __builtin_amdgcn_global_load_lds((gas_ptr)g, (las_ptr)l, 16, 0, 0);
}

__device__ __forceinline__ u16 f2bf(float f) {
    __hip_bfloat16 h = __float2bfloat16(f);
    return *(u16*)&h;
}
__device__ __forceinline__ float bf2f(u16 u) {
    return __uint_as_float(((u32)u) << 16);
}

// Bijective XCD-chunked swizzle (m204): consecutive blockIdx round-robin across the 8
// XCD L2s; remap so each XCD gets a CONTIGUOUS chunk of the grid (~2 whole batches ->
// q/k/att panels become L2-resident per XCD instead of 16-batch thrash).
__device__ __forceinline__ void xcd_remap(int& bx, int& by, int& bz) {
    const int nbx = gridDim.x, nby = gridDim.y;
    const int nwg = nbx * nby * gridDim.z;
    int bid = blockIdx.x + nbx * (blockIdx.y + nby * blockIdx.z);
    if ((nwg & 7) == 0) {
        const int q = nwg >> 3;
        bid = (bid & 7) * q + (bid >> 3);
    }
    bx = bid % nbx;
    int t2 = bid / nbx;
    by = t2 % nby;
    bz = t2 / nby;
}

// ---------------- cast f32 -> bf16 (vectorized x4) ----------------
__global__ __launch_bounds__(256) void cast_bf16_kernel(const float4* __restrict__ in,
                                                        ushort4* __restrict__ out, int n4) {
    int i = blockIdx.x * 256 + threadIdx.x;
    if (i >= n4) return;
    float4 v = in[i];
    ushort4 u;
    u.x = f2bf(v.x); u.y = f2bf(v.y); u.z = f2bf(v.z); u.w = f2bf(v.w);
    out[i] = u;
}

// ---------------- GroupNorm stats: one block per (b,g) ----------------
__global__ __launch_bounds__(256) void gn_stats_kernel(const float* __restrict__ x,
                                                       float* __restrict__ stats) {
    int bg = blockIdx.x;                       // b*NG + g
    const float4* p4 = (const float4*)(x + (size_t)bg * (CPG * HW));
    float s = 0.f, s2 = 0.f;
    for (int i = threadIdx.x; i < (CPG * HW) / 4; i += 256) {
        float4 v = p4[i];
        s  += v.x + v.y + v.z + v.w;
        s2 += v.x * v.x + v.y * v.y + v.z * v.z + v.w * v.w;
    }
    int lane = threadIdx.x & 63, wid = threadIdx.x >> 6;
    for (int off = 32; off; off >>= 1) {
        s  += __shfl_xor(s,  off, 64);
        s2 += __shfl_xor(s2, off, 64);
    }
    __shared__ float red[8];
    if (lane == 0) { red[wid * 2] = s; red[wid * 2 + 1] = s2; }
    __syncthreads();
    if (threadIdx.x == 0) {
        s = red[0] + red[2] + red[4] + red[6];
        s2 = red[1] + red[3] + red[5] + red[7];
        float mean = s / (float)(CPG * HW);
        float var  = s2 / (float)(CPG * HW) - mean * mean;
        stats[2 * bg]     = mean;
        stats[2 * bg + 1] = rsqrtf(var + EPS);
    }
}

// ------------- GroupNorm normalize + transpose -> xn_T [B, HW, C] bf16 -------------
__global__ __launch_bounds__(256) void gn_norm_kernel(const float* __restrict__ x,
                                                      const float* __restrict__ stats,
                                                      const float* __restrict__ gamma,
                                                      const float* __restrict__ beta,
                                                      __hip_bfloat16* __restrict__ xnT) {
    __shared__ float lds[64][65];
    int b  = blockIdx.y;
    int p0 = blockIdx.x * 64;
    int t = threadIdx.x;
    int lane = t & 63;
    int grp  = t >> 6;   // 0..3
    for (int cc = 0; cc < C_CH / 64; cc++) {
        int c0 = cc * 64;
        for (int i = 0; i < 16; i++) {
            int c = c0 + grp * 16 + i;
            float2 st = ((const float2*)stats)[b * NG + c / CPG];
            float ga = gamma[c], be = beta[c];
            float v = x[((size_t)b * C_CH + c) * HW + p0 + lane];
            lds[lane][grp * 16 + i] = (v - st.x) * st.y * ga + be;
        }
        __syncthreads();
        for (int i = 0; i < 16; i++) {
            int pp = grp * 16 + i;
            xnT[((size_t)b * HW + p0 + pp) * C_CH + c0 + lane] =
                __float2bfloat16(lds[pp][lane]);
        }
        __syncthreads();
    }
}

// ---------------- row softmax over att [rows][768] bf16, in place ----------------
__global__ __launch_bounds__(256) void softmax_kernel(__hip_bfloat16* __restrict__ att) {
    int row  = blockIdx.x * 4 + (threadIdx.x >> 6);
    int lane = threadIdx.x & 63;
    u16* p = (u16*)(att + (size_t)row * C_CH);
    float v[12];
    float m = -1e30f;
    for (int j = 0; j < 12; j++) {
        v[j] = bf2f(p[j * 64 + lane]);
        m = fmaxf(m, v[j]);
    }
    for (int off = 32; off; off >>= 1) m = fmaxf(m, __shfl_xor(m, off, 64));
    float s = 0.f;
    for (int j = 0; j < 12; j++) { v[j] = __expf(v[j] - m); s += v[j]; }
    for (int off = 32; off; off >>= 1) s += __shfl_xor(s, off, 64);
    float inv = 1.0f / s;
    for (int j = 0; j < 12; j++) p[j * 64 + lane] = f2bf(v[j] * inv);
}

// ---------------- NT GEMM: C[m,n] = scale * sum_k A[m,k]*B[n,k] (+bias/res) ----------------
// A: [M x K] row-major (rows at stride K), B: [N x K] row-major.
// Tile 128x128, BK=64, 4 waves each owning 64x64. global_load_lds staging with
// XOR-swizzled source so ds_read_b128 frag reads are conflict-free (R1-verified: 0 conflicts).
// Inner loop identical to the measured-best R1 kernel; additions are epilogue-only:
//  - optional transposed write for row-blocks >= vt_start (the V third of the QKV GEMM),
//    writing vT[p][c] as 8B-contiguous quads (lanes 0/16/32/48 form 32B segments).
//  - XCD-chunked block swizzle for L2 locality.
template<int OUT_F32>
__global__ __launch_bounds__(256, 2) void gemm_nt_kernel(
    const __hip_bfloat16* __restrict__ A, long sA,
    const __hip_bfloat16* __restrict__ B, long sB,
    void* __restrict__ Cout, long sC, int ldc,
    int K, float scale,
    const float* __restrict__ bias_row,
    const float* __restrict__ bias_col,
    const float* __restrict__ residual, long sR,
    __hip_bfloat16* __restrict__ vt_out, long sVT, int vt_start)
{
    __shared__ __hip_bfloat16 ldsA[128 * 64];
    __shared__ __hip_bfloat16 ldsB[128 * 64];
    int bxx, byy, bzz;
    xcd_remap(bxx, byy, bzz);
    const int t  = threadIdx.x;
    const int b  = bzz;
    const int m0 = byy * 128;
    const int n0 = bxx * 128;
    const int lane = t & 63;
    const int wid  = t >> 6;
    const int wm = wid >> 1, wn = wid & 1;
    const int lrow = lane & 15, lk = lane >> 4;

    // staging: chunk idx = r*256 + t -> row = idx/8, chunk = idx%8 (16B chunks)
    const int srow   = t >> 3;                       // + r*32
    const int schunk = t & 7;
    const int kphys  = (schunk ^ (srow & 7)) * 8;    // element offset in [0,64)

    const __hip_bfloat16* aBase = A + (size_t)b * sA + (size_t)(m0 + srow) * K + kphys;
    const __hip_bfloat16* bBase = B + (size_t)b * sB + (size_t)(n0 + srow) * K + kphys;
    const int ldsDst = (t & ~63) * 8;                // wave-uniform elem offset; +r*2048

    f32x4 acc[4][4] = {};

    const int nk = K >> 6;
    for (int kt = 0; kt < nk; kt++) {
        __syncthreads();
        const __hip_bfloat16* ak = aBase + (size_t)kt * 64;
        const __hip_bfloat16* bk = bBase + (size_t)kt * 64;
        for (int r = 0; r < 4; r++)
            load_lds16(ak + (size_t)r * 32 * K, &ldsA[ldsDst + r * 2048]);
        for (int r = 0; r < 4; r++)
            load_lds16(bk + (size_t)r * 32 * K, &ldsB[ldsDst + r * 2048]);
        __syncthreads();
        for (int h = 0; h < 2; h++) {
            bf16x8 af[4], bfr[4];
            const int lc = h * 4 + lk;
            for (int i = 0; i < 4; i++) {
                int row = wm * 64 + i * 16 + lrow;
                int pc = lc ^ (row & 7);
                af[i] = *(const bf16x8*)&ldsA[row * 64 + pc * 8];
            }
            for (int i = 0; i < 4; i++) {
                int col = wn * 64 + i * 16 + lrow;
                int pc = lc ^ (col & 7);
                bfr[i] = *(const bf16x8*)&ldsB[col * 64 + pc * 8];
            }
            for (int i = 0; i < 4; i++)
                for (int j = 0; j < 4; j++)
                    acc[i][j] = __builtin_amdgcn_mfma_f32_16x16x32_bf16(
                        af[i], bfr[j], acc[i][j], 0, 0, 0);
        }
    }

    if (vt_out && m0 >= vt_start) {
        // V third of the QKV GEMM: write transposed, vT[p][o-vt_start]
        __hip_bfloat16* vtp = vt_out + (size_t)b * sVT;
        for (int i = 0; i < 4; i++)
            for (int j = 0; j < 4; j++) {
                int row = m0 + wm * 64 + i * 16 + lk * 4;   // o index (row..row+3)
                int col = n0 + wn * 64 + j * 16 + lrow;     // p index
                f32x4 a = acc[i][j];
                ushort4 u;
                u.x = f2bf(a[0] * scale + (bias_row ? bias_row[row + 0] : 0.f));
                u.y = f2bf(a[1] * scale + (bias_row ? bias_row[row + 1] : 0.f));
                u.z = f2bf(a[2] * scale + (bias_row ? bias_row[row + 2] : 0.f));
                u.w = f2bf(a[3] * scale + (bias_row ? bias_row[row + 3] : 0.f));
                *(ushort4*)(vtp + (size_t)col * C_CH + (row - vt_start)) = u;
            }
        return;
    }

    __hip_bfloat16* outB = (__hip_bfloat16*)Cout;
    float* outF = (float*)Cout;
    for (int i = 0; i < 4; i++)
        for (int j = 0; j < 4; j++) {
            int row = m0 + wm * 64 + i * 16 + lk * 4;
            int col = n0 + wn * 64 + j * 16 + lrow;
            f32x4 a = acc[i][j];
            for (int r = 0; r < 4; r++) {
                int rr = row + r;
                float v = a[r] * scale;
                if (bias_row) v += bias_row[rr];
                if (bias_col) v += bias_col[col];
                if (residual) v += residual[(size_t)b * sR + (size_t)rr * ldc + col];
                size_t off = (size_t)b * sC + (size_t)rr * ldc + col;
                if (OUT_F32) outF[off] = v;
                else         outB[off] = __float2bfloat16(v);
            }
        }
}

extern "C" void kernel_launch(void* const* d_in, const int* in_sizes, int n_in,
                              void* d_out, int out_size, void* d_ws, size_t ws_size,
                              hipStream_t stream) {
    const float* x     = (const float*)d_in[0];
    const float* gamma = (const float*)d_in[1];
    const float* beta  = (const float*)d_in[2];
    const float* w_qkv = (const float*)d_in[3];
    const float* b_qkv = (const float*)d_in[4];
    const float* w_out = (const float*)d_in[5];
    const float* b_out = (const float*)d_in[6];

    char* ws = (char*)d_ws;
    size_t off = 0;
    auto alloc = [&](size_t bytes) {
        void* p = ws + off;
        off += (bytes + 255) & ~(size_t)255;
        return p;
    };
    __hip_bfloat16* xnT   = (__hip_bfloat16*)alloc((size_t)BATCH * HW * C_CH * 2);
    __hip_bfloat16* wqkvB = (__hip_bfloat16*)alloc((size_t)3 * C_CH * C_CH * 2);
    __hip_bfloat16* woutB = (__hip_bfloat16*)alloc((size_t)C_CH * C_CH * 2);
    __hip_bfloat16* qk    = (__hip_bfloat16*)alloc((size_t)BATCH * 2 * C_CH * HW * 2);
    __hip_bfloat16* vT    = (__hip_bfloat16*)alloc((size_t)BATCH * HW * C_CH * 2);
    __hip_bfloat16* att   = (__hip_bfloat16*)alloc((size_t)BATCH * C_CH * C_CH * 2);
    __hip_bfloat16* outT  = (__hip_bfloat16*)alloc((size_t)BATCH * HW * C_CH * 2);
    float* stats          = (float*)alloc((size_t)BATCH * NG * 2 * 4);

    // 1) cast weights to bf16
    {
        int n4 = (3 * C_CH * C_CH) / 4;
        cast_bf16_kernel<<<(n4 + 255) / 256, 256, 0, stream>>>(
            (const float4*)w_qkv, (ushort4*)wqkvB, n4);
        int n4b = (C_CH * C_CH) / 4;
        cast_bf16_kernel<<<(n4b + 255) / 256, 256, 0, stream>>>(
            (const float4*)w_out, (ushort4*)woutB, n4b);
    }
    // 2) GroupNorm stats + normalize/transpose
    gn_stats_kernel<<<BATCH * NG, 256, 0, stream>>>(x, stats);
    gn_norm_kernel<<<dim3(HW / 64, BATCH), 256, 0, stream>>>(x, stats, gamma, beta, xnT);

    // 3) QKV GEMM (merged): M=2304, N=1024, K=768.
    //    o < 1536 -> qk[b,o,p]; o >= 1536 -> transposed into vT[b,p,o-1536].
    gemm_nt_kernel<0><<<dim3(HW / 128, 2304 / 128, BATCH), 256, 0, stream>>>(
        wqkvB, 0, xnT, (long)HW * C_CH, qk, (long)2 * C_CH * HW, HW,
        C_CH, 1.0f, b_qkv, nullptr, nullptr, 0,
        vT, (long)HW * C_CH, 2 * C_CH);

    // 4) GEMM2: att[b,i,j] = q.k^T * hw^-0.5  (M=768,N=768,K=1024)
    gemm_nt_kernel<0><<<dim3(C_CH / 128, C_CH / 128, BATCH), 256, 0, stream>>>(
        qk, (long)2 * C_CH * HW, qk + (size_t)C_CH * HW, (long)2 * C_CH * HW,
        att, (long)C_CH * C_CH, C_CH,
        HW, 1.0f / 32.0f, nullptr, nullptr, nullptr, 0,
        nullptr, 0, 0);

    // 5) softmax rows
    softmax_kernel<<<(BATCH * C_CH) / 4, 256, 0, stream>>>(att);

    // 6) GEMM3: out_T[b,p,i] = v_T . att^T  (M=1024,N=768,K=768)
    gemm_nt_kernel<0><<<dim3(C_CH / 128, HW / 128, BATCH), 256, 0, stream>>>(
        vT, (long)HW * C_CH, att, (long)C_CH * C_CH, outT, (long)HW * C_CH, C_CH,
        C_CH, 1.0f, nullptr, nullptr, nullptr, 0,
        nullptr, 0, 0);

    // 7) GEMM4: out[b,o,p] = w_out . out_T^T + b_out + x  (M=768,N=1024,K=768), f32 out
    gemm_nt_kernel<1><<<dim3(HW / 128, C_CH / 128, BATCH), 256, 0, stream>>>(
        woutB, 0, outT, (long)HW * C_CH, (float*)d_out, (long)C_CH * HW, HW,
        C_CH, 1.0f, b_out, nullptr, x, (long)C_CH * HW,
        nullptr, 0, 0);
}